// Round 2
// baseline (5824.951 us; speedup 1.0000x reference)
//
#include <hip/hip_runtime.h>
#include <math.h>

#define NDIM 64
#define PITCH 68            // 64 words padded to 68: float4-aligned rows, conflict-free lane reads
#define MAXSWEEPS 20

// One wave (64 lanes) per 64x64 SPD matrix. Lane j owns column j in registers.
// One-sided (Hestenes) Jacobi, XOR pair ordering (direction alternates per sweep
// to break ordering cycles); partner column via ds_bpermute. Rotations are ALWAYS
// applied (no threshold skip -> no stagnation floor); the ballot threshold is only
// the convergence detector. Final: lambda_k = ||m_k||, out = sum_k log(lambda_k+eps)/lambda_k^2 * m_k m_k^T.
__global__ __launch_bounds__(64, 2)
void logeig_jacobi_kernel(const float* __restrict__ in, float* __restrict__ out)
{
    const int b    = blockIdx.x;
    const int lane = threadIdx.x;
    const float* A = in  + (size_t)b * (NDIM * NDIM);
    float*       O = out + (size_t)b * (NDIM * NDIM);

    __shared__ float lds[NDIM * PITCH + NDIM];  // M^T rows + w[]

    // stage in: x[i] = A[i][lane]  (column 'lane'); coalesced across lanes
    float x[NDIM];
#pragma unroll
    for (int i = 0; i < NDIM; ++i)
        x[i] = A[i * NDIM + lane];

    float alpha = 0.0f;
#pragma unroll
    for (int i = 0; i < NDIM; ++i) alpha = fmaf(x[i], x[i], alpha);

#pragma unroll 1
    for (int sweep = 0; sweep < MAXSWEEPS; ++sweep) {
        // refresh self-dot (kills incremental-update drift)
        float a2 = 0.0f;
#pragma unroll
        for (int i = 0; i < NDIM; ++i) a2 = fmaf(x[i], x[i], a2);
        alpha = a2;

        bool sweep_rot = false;
#pragma unroll 1
        for (int mi = 1; mi < NDIM; ++mi) {
            const int m    = (sweep & 1) ? (NDIM - mi) : mi;  // alternate direction
            const int pidx = (lane ^ m) << 2;

            // pull partner column (64 b32 bpermutes)
            float y[NDIM];
#pragma unroll
            for (int i = 0; i < NDIM; ++i)
                y[i] = __int_as_float(__builtin_amdgcn_ds_bpermute(pidx, __float_as_int(x[i])));

            // cross dot: identical product order on both lanes of a pair -> bitwise-identical gamma
            float gamma = 0.0f;
#pragma unroll
            for (int i = 0; i < NDIM; ++i) gamma = fmaf(x[i], y[i], gamma);

            const float other = __int_as_float(__builtin_amdgcn_ds_bpermute(pidx, __float_as_int(alpha)));

            const bool  is_p = lane < (lane ^ m);
            const float aa = is_p ? alpha : other;  // alpha (p's self-dot)
            const float bb = is_p ? other : alpha;  // beta  (q's self-dot)

            // convergence detector ONLY (rel off-diag > 1e-6); does not gate the rotation
            const bool big = (gamma * gamma) > (1e-12f * aa * bb);
            if (__ballot(big) != 0ull) sweep_rot = true;

            // Golub-Van-Loan symmetric Schur: zeta=(b-a)/(2g), t=sgn/(|z|+sqrt(1+z^2))
            // gamma==0 exactly would give 0/0 -> guard with 'rot' select below.
            const bool rot = (gamma != 0.0f);
            float zeta = (bb - aa) / (2.0f * gamma);
            float az   = fabsf(zeta);
            float t    = 1.0f / (az + sqrtf(1.0f + az * az));
            t = (zeta < 0.0f) ? -t : t;
            float cc = 1.0f / sqrtf(1.0f + t * t);
            float ss = t * cc;

            const float sgn = is_p ? -1.0f : 1.0f;     // p: x' = c x - s y ; q: x' = c x + s y
            const float c_r = rot ? cc : 1.0f;
            const float s_r = rot ? sgn * ss : 0.0f;
            const float tg  = rot ? sgn * t * gamma : 0.0f;

#pragma unroll
            for (int i = 0; i < NDIM; ++i)
                x[i] = fmaf(c_r, x[i], s_r * y[i]);
            alpha += tg;                                // alpha' = alpha -/+ t*gamma
        }
        if (!sweep_rot) break;   // all pairs below rel 1e-6 -> converged
    }

    // eigenvalue & weight: lambda = ||m||, w = log(lambda + 1e-9) / lambda^2
    float af = 0.0f;
#pragma unroll
    for (int i = 0; i < NDIM; ++i) af = fmaf(x[i], x[i], af);
    const float lam = sqrtf(af);
    const float w   = logf(lam + 1e-9f) / af;

    // publish M^T row 'lane' (= column 'lane' of M) and w
    float4* row = (float4*)&lds[lane * PITCH];
#pragma unroll
    for (int t4 = 0; t4 < NDIM / 4; ++t4)
        row[t4] = make_float4(x[4 * t4 + 0], x[4 * t4 + 1], x[4 * t4 + 2], x[4 * t4 + 3]);
    lds[NDIM * PITCH + lane] = w;
    __syncthreads();

    // O[:,lane] = sum_k (w_k * m_{lane,k}) * m_{:,k}
    float acc[NDIM];
#pragma unroll
    for (int i = 0; i < NDIM; ++i) acc[i] = 0.0f;

#pragma unroll 1
    for (int k = 0; k < NDIM; ++k) {
        const float wk  = lds[NDIM * PITCH + k];     // broadcast
        const float mjk = lds[k * PITCH + lane];     // conflict-free
        const float zk  = wk * mjk;
        const float4* rowk = (const float4*)&lds[k * PITCH];
#pragma unroll
        for (int t4 = 0; t4 < NDIM / 4; ++t4) {
            const float4 v = rowk[t4];               // broadcast float4
            acc[4 * t4 + 0] = fmaf(zk, v.x, acc[4 * t4 + 0]);
            acc[4 * t4 + 1] = fmaf(zk, v.y, acc[4 * t4 + 1]);
            acc[4 * t4 + 2] = fmaf(zk, v.z, acc[4 * t4 + 2]);
            acc[4 * t4 + 3] = fmaf(zk, v.w, acc[4 * t4 + 3]);
        }
    }

#pragma unroll
    for (int i = 0; i < NDIM; ++i)
        O[i * NDIM + lane] = acc[i];   // coalesced across lanes
}

extern "C" void kernel_launch(void* const* d_in, const int* in_sizes, int n_in,
                              void* d_out, int out_size, void* d_ws, size_t ws_size,
                              hipStream_t stream)
{
    const float* in  = (const float*)d_in[0];
    float*       out = (float*)d_out;
    const int nmat = out_size / (NDIM * NDIM);   // 256*32 = 8192
    hipLaunchKernelGGL(logeig_jacobi_kernel, dim3(nmat), dim3(64), 0, stream, in, out);
}

// Round 3
// 5772.037 us; speedup vs baseline: 1.0092x; 1.0092x over previous
//
#include <hip/hip_runtime.h>
#include <math.h>

#define NDIM 64
#define PITCH 68          // chunk-row pitch in words: float4-aligned, conflict-free
#define KC 16             // columns staged per reconstruction chunk
#define MAXSWEEPS 20

// One wave (64 lanes) per 64x64 SPD matrix. Lane j owns column j in registers.
// One-sided (Hestenes) Jacobi, XOR pair ordering, alternating direction per sweep.
// Rotations always applied; ballot threshold (rel 3.2e-5, above fp32 dot noise)
// is ONLY the convergence detector. Reconstruction: chunked LDS staging (16 cols
// = 4.6 KB) so LDS doesn't cap occupancy; launch_bounds(64,3) keeps x+y in VGPRs
// at ~3 waves/SIMD.
__global__ __launch_bounds__(64, 3)
void logeig_jacobi_kernel(const float* __restrict__ in, float* __restrict__ out)
{
    const int b    = blockIdx.x;
    const int lane = threadIdx.x;
    const float* A = in  + (size_t)b * (NDIM * NDIM);
    float*       O = out + (size_t)b * (NDIM * NDIM);

    __shared__ float ldsM[KC * PITCH];   // 16 staged columns (column j -> row j-c)
    __shared__ float ldsW[NDIM];         // per-column weights

    // stage in: x[i] = A[i][lane]  (column 'lane'); coalesced across lanes
    float x[NDIM];
#pragma unroll
    for (int i = 0; i < NDIM; ++i)
        x[i] = A[i * NDIM + lane];

    float alpha = 0.0f;
#pragma unroll
    for (int i = 0; i < NDIM; ++i) alpha = fmaf(x[i], x[i], alpha);

#pragma unroll 1
    for (int sweep = 0; sweep < MAXSWEEPS; ++sweep) {
        // refresh self-dot (kills incremental-update drift)
        float a2 = 0.0f;
#pragma unroll
        for (int i = 0; i < NDIM; ++i) a2 = fmaf(x[i], x[i], a2);
        alpha = a2;

        bool sweep_rot = false;
#pragma unroll 1
        for (int mi = 1; mi < NDIM; ++mi) {
            const int m    = (sweep & 1) ? (NDIM - mi) : mi;  // alternate direction
            const int pidx = (lane ^ m) << 2;

            // pull partner column (64 b32 bpermutes)
            float y[NDIM];
#pragma unroll
            for (int i = 0; i < NDIM; ++i)
                y[i] = __int_as_float(__builtin_amdgcn_ds_bpermute(pidx, __float_as_int(x[i])));

            // cross dot, 4 partial accumulators; product order identical on both
            // lanes of a pair (mult commutes, same grouping) -> bitwise-same gamma
            float g0 = 0.f, g1 = 0.f, g2 = 0.f, g3 = 0.f;
#pragma unroll
            for (int i = 0; i < NDIM; i += 4) {
                g0 = fmaf(x[i + 0], y[i + 0], g0);
                g1 = fmaf(x[i + 1], y[i + 1], g1);
                g2 = fmaf(x[i + 2], y[i + 2], g2);
                g3 = fmaf(x[i + 3], y[i + 3], g3);
            }
            const float gamma = (g0 + g1) + (g2 + g3);

            const float other = __int_as_float(__builtin_amdgcn_ds_bpermute(pidx, __float_as_int(alpha)));

            const bool  is_p = lane < (lane ^ m);
            const float aa = is_p ? alpha : other;  // alpha (p's self-dot)
            const float bb = is_p ? other : alpha;  // beta  (q's self-dot)

            // convergence detector ONLY (rel 3.2e-5 > fp32 dot noise ~5e-7);
            // does not gate the rotation -> no stagnation, and it can actually fire
            const bool big = (gamma * gamma) > (1e-9f * aa * bb);
            if (__ballot(big) != 0ull) sweep_rot = true;

            // Golub-Van-Loan symmetric Schur; gamma==0 would be 0/0 -> 'rot' select
            const bool rot = (gamma != 0.0f);
            float zeta = (bb - aa) / (2.0f * gamma);
            float az   = fabsf(zeta);
            float t    = 1.0f / (az + sqrtf(1.0f + az * az));
            t = (zeta < 0.0f) ? -t : t;
            float cc = 1.0f / sqrtf(1.0f + t * t);
            float ss = t * cc;

            const float sgn = is_p ? -1.0f : 1.0f;  // p: x' = c x - s y ; q: x' = c x + s y
            const float c_r = rot ? cc : 1.0f;
            const float s_r = rot ? sgn * ss : 0.0f;
            const float tg  = rot ? sgn * t * gamma : 0.0f;

#pragma unroll
            for (int i = 0; i < NDIM; ++i)
                x[i] = fmaf(c_r, x[i], s_r * y[i]);
            alpha += tg;                            // alpha' = alpha -/+ t*gamma
        }
        if (!sweep_rot) break;   // all pairs below rel 3.2e-5 -> converged
    }

    // eigenvalue & weight: lambda = ||m||, w = log(lambda + 1e-9) / lambda^2
    float af = 0.0f;
#pragma unroll
    for (int i = 0; i < NDIM; ++i) af = fmaf(x[i], x[i], af);
    const float lam = sqrtf(af);
    ldsW[lane] = logf(lam + 1e-9f) / af;   // first __syncthreads below orders this

    // O[:,lane] = sum_k (w_k * m_{lane,k}) * m_{:,k}, staged KC columns at a time
    float acc[NDIM];
#pragma unroll
    for (int i = 0; i < NDIM; ++i) acc[i] = 0.0f;

#pragma unroll 1
    for (int c = 0; c < NDIM; c += KC) {
        __syncthreads();   // prev chunk fully read (and ldsW visible on c==0)
        if (lane >= c && lane < c + KC) {
            float4* row = (float4*)&ldsM[(lane - c) * PITCH];
#pragma unroll
            for (int t4 = 0; t4 < NDIM / 4; ++t4)
                row[t4] = make_float4(x[4 * t4 + 0], x[4 * t4 + 1], x[4 * t4 + 2], x[4 * t4 + 3]);
        }
        __syncthreads();
#pragma unroll 1
        for (int kk = 0; kk < KC; ++kk) {
            const float wk  = ldsW[c + kk];             // broadcast
            const float mlk = ldsM[kk * PITCH + lane];  // consecutive -> conflict-free
            const float zk  = wk * mlk;
            const float4* rowk = (const float4*)&ldsM[kk * PITCH];
#pragma unroll
            for (int t4 = 0; t4 < NDIM / 4; ++t4) {
                const float4 v = rowk[t4];              // broadcast float4
                acc[4 * t4 + 0] = fmaf(zk, v.x, acc[4 * t4 + 0]);
                acc[4 * t4 + 1] = fmaf(zk, v.y, acc[4 * t4 + 1]);
                acc[4 * t4 + 2] = fmaf(zk, v.z, acc[4 * t4 + 2]);
                acc[4 * t4 + 3] = fmaf(zk, v.w, acc[4 * t4 + 3]);
            }
        }
    }

#pragma unroll
    for (int i = 0; i < NDIM; ++i)
        O[i * NDIM + lane] = acc[i];   // coalesced across lanes
}

extern "C" void kernel_launch(void* const* d_in, const int* in_sizes, int n_in,
                              void* d_out, int out_size, void* d_ws, size_t ws_size,
                              hipStream_t stream)
{
    const float* in  = (const float*)d_in[0];
    float*       out = (float*)d_out;
    const int nmat = out_size / (NDIM * NDIM);   // 256*32 = 8192
    hipLaunchKernelGGL(logeig_jacobi_kernel, dim3(nmat), dim3(64), 0, stream, in, out);
}